// Round 6
// baseline (2957.414 us; speedup 1.0000x reference)
//
#include <hip/hip_runtime.h>

// 2-layer LSTM encoder, B=128, T=1024, F=1, HID=128, EMB=64.
// R15 = split-CU pipeline. R10 (rebalance) nulled, R14 (lag-2 prefetch) gave
// only -6%: per-CU step is pinned by matrix-pipe occupancy (224 MFMAs/step /
// 4 SIMD * 19.4cy = 1086cy of the ~1594cy step). Only more CUs cuts it.
// 128 batches, 256 CUs -> half the chip was idle.
//   blocks 0..127  : L1 producer (batch b). 8 waves, R9's verified tile map
//     (wave w owns N-tiles {w+8g}, cells 16w+l). 620cy pipe/SIMD.
//     h1(s) -> own LDS (recurrence) + f32 ring in d_ws via agent-scope
//     atomics (LLC, the only cross-XCD-coherent path).
//     Latency discipline: at top of step s, FIRST publish flag=s-1 (release;
//     free -- prior stores drained by last barrier), THEN ring-store h1(s-1)
//     from a register (a full step to retire before this step's barrier
//     vmcnt(0) drain -> no LLC ack on the critical path).
//   blocks 128..255: L2 consumer (batch b-128). Waves 0-3 = R10's verified
//     L2 compute (24 MFMAs each, 465cy/SIMD); wave 4 = stage wave: polls
//     flag, agent-loads ring h1(m+1), rte-cvt to f16, LDS double-buffer --
//     LLC latency hidden under compute of step m. Waves 5-7 idle.
//     Consumer self-stabilizes ~2 steps behind producer; off critical path.
// Ring: d_ws = u32 cnt[128] (zeroed per launch by hipMemsetAsync) +
//       u32 ring[128][8][128] (f32 bits). Producer rewrites slot s&7 at
//       s+8; consumer lag <=~2 -> 6-step margin.
// Co-residency: 256 blocks * 8 waves = 2048 waves << capacity -> all
// resident; spin-wait cannot deadlock.
// Numerics: h1 reaches L2 via f32 ring + rte (_Float16) cvt = same rounding
// as the old shared-LDS path -> absmax must stay bit-identical 4.88e-4.

#define TB     1024
#define HID1   128
#define EMB2   64
#define RING_D 8

typedef _Float16 f16x8 __attribute__((ext_vector_type(8)));
typedef float    f32x4 __attribute__((ext_vector_type(4)));

#define MFMA16(a,b,c) __builtin_amdgcn_mfma_f32_16x16x32_f16((a),(b),(c),0,0,0)

static __device__ __forceinline__ float fast_exp2(float x){
#if __has_builtin(__builtin_amdgcn_exp2f)
  return __builtin_amdgcn_exp2f(x);
#else
  return __exp2f(x);
#endif
}
static __device__ __forceinline__ float fast_rcp(float x){
#if __has_builtin(__builtin_amdgcn_rcpf)
  return __builtin_amdgcn_rcpf(x);
#else
  return 1.0f / x;
#endif
}
static __device__ __forceinline__ float sigmoid_f(float x){
  return fast_rcp(1.0f + fast_exp2(-1.44269504088896340736f * x));
}
static __device__ __forceinline__ float tanh_f(float x){
  return 1.0f - 2.0f * fast_rcp(1.0f + fast_exp2(2.88539008177792681472f * x));
}

static __device__ __forceinline__ f16x8 load_frag(const float* p){
  f16x8 r;
  #pragma unroll
  for (int j = 0; j < 8; ++j) r[j] = (_Float16)p[j];
  return r;
}

__launch_bounds__(512, 1)
__global__ void lstm2_kernel(const float* __restrict__ x,
                             const float* __restrict__ w_ih1,
                             const float* __restrict__ w_hh1,
                             const float* __restrict__ b_ih1,
                             const float* __restrict__ b_hh1,
                             const float* __restrict__ w_ih2,
                             const float* __restrict__ w_hh2,
                             const float* __restrict__ b_ih2,
                             const float* __restrict__ b_hh2,
                             float* __restrict__ out,
                             unsigned int* __restrict__ ws)
{
  __shared__ __align__(16) float    xs[TB];        // L1 blocks only
  __shared__ __align__(16) _Float16 SH1[2][HID1];  // L1: h1 pingpong; L2: staged h1
  __shared__ __align__(16) _Float16 SH2[2][EMB2];  // L2 blocks only

  const int t    = threadIdx.x;   // 0..511
  const int l    = t & 63;
  const int w    = t >> 6;        // wave 0..7
  const int col  = l & 15;
  const int quad = l >> 4;

  unsigned int* cnt  = ws;        // [128] published-step counters
  unsigned int* ring = ws + 128;  // [128][RING_D][HID1] f32-bits

  const f32x4 zacc = {0.0f, 0.0f, 0.0f, 0.0f};

  if (blockIdx.x < 128){
    // ================= L1 producer block (batch bb) =================
    const int bb = blockIdx.x;

    // R9 verified layout: wave w owns N-tiles {w+8g}, ew lanes<16, cell 16w+l.
    f16x8 B1[4][4];
    float biasA[4], wxA[4];
    #pragma unroll
    for (int g = 0; g < 4; ++g){
      const int nA = (w + 8*g)*16 + col;
      biasA[g] = b_ih1[nA] + b_hh1[nA];
      wxA[g]   = w_ih1[nA];                     // w_ih1 is (512,1)
      #pragma unroll
      for (int k = 0; k < 4; ++k)
        B1[g][k] = load_frag(w_hh1 + nA*HID1 + k*32 + quad*8);
    }
    xs[t]       = x[bb * TB + t];
    xs[t + 512] = x[bb * TB + t + 512];
    if (t < HID1){ SH1[0][t] = (_Float16)0.0f; SH1[1][t] = (_Float16)0.0f; }
    __syncthreads();

    float c1 = 0.0f, hprev = 0.0f;
    const int cellA = 16*w + l;      // valid when l<16

    // iter 0: h1(0) = f(x0), no MFMA -> SH1[0]
    if (l < 16){
      const float xt = xs[0];
      float g4[4];
      #pragma unroll
      for (int g = 0; g < 4; ++g) g4[g] = __builtin_fmaf(xt, wxA[g], biasA[g]);
      c1 = sigmoid_f(g4[1]) * c1 + sigmoid_f(g4[0]) * tanh_f(g4[2]);
      const float hv = sigmoid_f(g4[3]) * tanh_f(c1);
      hprev = hv;
      SH1[0][cellA] = (_Float16)hv;
    }
    __syncthreads();

    #pragma unroll 1
    for (int s = 1; s < TB; ++s){
      // publish h1(s-2) (its ring store drained at last barrier), THEN issue
      // the h1(s-1) ring store (has a whole step to retire).
      if (w == 0 && l == 0 && s >= 2)
        __hip_atomic_store(&cnt[bb], (unsigned)(s-1),
                           __ATOMIC_RELEASE, __HIP_MEMORY_SCOPE_AGENT);
      if (l < 16)
        __hip_atomic_store(&ring[((unsigned)bb*RING_D + ((s-1)&(RING_D-1)))*HID1 + cellA],
                           __float_as_uint(hprev),
                           __ATOMIC_RELAXED, __HIP_MEMORY_SCOPE_AGENT);

      const f16x8* pA1 = (const f16x8*)&SH1[(s+1)&1][0];
      const f16x8 a10 = pA1[quad],     a11 = pA1[4+quad],
                  a12 = pA1[8+quad],   a13 = pA1[12+quad];
      f32x4 aLo[4], aHi[4];
      #pragma unroll
      for (int g = 0; g < 4; ++g){
        aLo[g] = MFMA16(a10, B1[g][0], zacc);
        aHi[g] = MFMA16(a12, B1[g][2], zacc);
      }
      #pragma unroll
      for (int g = 0; g < 4; ++g){
        aLo[g] = MFMA16(a11, B1[g][1], aLo[g]);
        aHi[g] = MFMA16(a13, B1[g][3], aHi[g]);
      }
      if (l < 16){
        float g4[4];
        #pragma unroll
        for (int g = 0; g < 4; ++g)
          g4[g] = aLo[g][0] + aHi[g][0] + __builtin_fmaf(xs[s], wxA[g], biasA[g]);
        c1 = sigmoid_f(g4[1]) * c1 + sigmoid_f(g4[0]) * tanh_f(g4[2]);
        const float hv = sigmoid_f(g4[3]) * tanh_f(c1);
        hprev = hv;
        SH1[s&1][cellA] = (_Float16)hv;
      }
      __syncthreads();
    }
    // tail: store h1(1023), drain, publish 1024
    if (l < 16)
      __hip_atomic_store(&ring[((unsigned)bb*RING_D + ((TB-1)&(RING_D-1)))*HID1 + cellA],
                         __float_as_uint(hprev),
                         __ATOMIC_RELAXED, __HIP_MEMORY_SCOPE_AGENT);
    __syncthreads();
    if (w == 0 && l == 0)
      __hip_atomic_store(&cnt[bb], (unsigned)TB,
                         __ATOMIC_RELEASE, __HIP_MEMORY_SCOPE_AGENT);

  } else {
    // ================= L2 consumer block (batch bb) =================
    const int bb = blockIdx.x - 128;

    // R10 verified layout (waves 0-3): tile nB=(4g+w)*16+col, cells 16w+l.
    f16x8 B2i[4][4], B2h[4][2];
    float biasB[4];
    if (w < 4){
      #pragma unroll
      for (int g = 0; g < 4; ++g){
        const int nB = (4*g + w)*16 + col;
        biasB[g] = b_ih2[nB] + b_hh2[nB];
        #pragma unroll
        for (int k = 0; k < 4; ++k)
          B2i[g][k] = load_frag(w_ih2 + nB*HID1 + k*32 + quad*8);
        #pragma unroll
        for (int k = 0; k < 2; ++k)
          B2h[g][k] = load_frag(w_hh2 + nB*EMB2 + k*32 + quad*8);
      }
    }
    if (t < EMB2){ SH2[0][t] = (_Float16)0.0f; SH2[1][t] = (_Float16)0.0f; }
    __syncthreads();

    // prologue: stage h1(0) -> SH1[0]
    if (w == 4){
      while (__hip_atomic_load(&cnt[bb], __ATOMIC_ACQUIRE,
                               __HIP_MEMORY_SCOPE_AGENT) < 1u)
        __builtin_amdgcn_s_sleep(1);
      const unsigned base = ((unsigned)bb*RING_D + 0)*HID1;
      const unsigned r0 = __hip_atomic_load(&ring[base + 2*l],
                              __ATOMIC_RELAXED, __HIP_MEMORY_SCOPE_AGENT);
      const unsigned r1 = __hip_atomic_load(&ring[base + 2*l + 1],
                              __ATOMIC_RELAXED, __HIP_MEMORY_SCOPE_AGENT);
      union { _Float16 h[2]; unsigned u; } cv;
      cv.h[0] = (_Float16)__uint_as_float(r0);   // rte, same as producer LDS path
      cv.h[1] = (_Float16)__uint_as_float(r1);
      ((unsigned*)&SH1[0][0])[l] = cv.u;
    }
    __syncthreads();

    float c2 = 0.0f;
    #pragma unroll 1
    for (int m = 0; m < TB; ++m){
      if (w < 4){
        const f16x8* pA2 = (const f16x8*)&SH2[(m+1)&1][0];   // h2(m-1)
        const f16x8 a20 = pA2[quad], a21 = pA2[4+quad];
        const f16x8* pA1 = (const f16x8*)&SH1[m&1][0];       // h1(m) staged
        const f16x8 a10 = pA1[quad],    a11 = pA1[4+quad],
                    a12 = pA1[8+quad],  a13 = pA1[12+quad];
        f32x4 lo[4], hi[4];
        #pragma unroll
        for (int g = 0; g < 4; ++g){
          lo[g] = MFMA16(a10, B2i[g][0], zacc);
          hi[g] = MFMA16(a12, B2i[g][2], zacc);
        }
        #pragma unroll
        for (int g = 0; g < 4; ++g){
          lo[g] = MFMA16(a11, B2i[g][1], lo[g]);
          hi[g] = MFMA16(a13, B2i[g][3], hi[g]);
        }
        #pragma unroll
        for (int g = 0; g < 4; ++g){
          lo[g] = MFMA16(a20, B2h[g][0], lo[g]);
          hi[g] = MFMA16(a21, B2h[g][1], hi[g]);
        }
        if (l < 16){
          float g4[4];
          #pragma unroll
          for (int g = 0; g < 4; ++g) g4[g] = lo[g][0] + hi[g][0] + biasB[g];
          c2 = sigmoid_f(g4[1]) * c2 + sigmoid_f(g4[0]) * tanh_f(g4[2]);
          const float hv = sigmoid_f(g4[3]) * tanh_f(c2);
          if (m < TB-1) SH2[m&1][16*w + l] = (_Float16)hv;
          else          out[bb * EMB2 + 16*w + l] = hv;
        }
      } else if (w == 4 && m < TB-1){
        // stage h1(m+1) -> SH1[(m+1)&1] while waves 0-3 compute step m
        const unsigned need = (unsigned)(m + 2);
        while (__hip_atomic_load(&cnt[bb], __ATOMIC_ACQUIRE,
                                 __HIP_MEMORY_SCOPE_AGENT) < need)
          __builtin_amdgcn_s_sleep(1);
        const unsigned base = ((unsigned)bb*RING_D + ((m+1)&(RING_D-1)))*HID1;
        const unsigned r0 = __hip_atomic_load(&ring[base + 2*l],
                                __ATOMIC_RELAXED, __HIP_MEMORY_SCOPE_AGENT);
        const unsigned r1 = __hip_atomic_load(&ring[base + 2*l + 1],
                                __ATOMIC_RELAXED, __HIP_MEMORY_SCOPE_AGENT);
        union { _Float16 h[2]; unsigned u; } cv;
        cv.h[0] = (_Float16)__uint_as_float(r0);
        cv.h[1] = (_Float16)__uint_as_float(r1);
        ((unsigned*)&SH1[(m+1)&1][0])[l] = cv.u;
      }
      __syncthreads();
    }
  }
}

extern "C" void kernel_launch(void* const* d_in, const int* in_sizes, int n_in,
                              void* d_out, int out_size, void* d_ws, size_t ws_size,
                              hipStream_t stream) {
  // zero the 128 flag counters each launch (stream-ordered, graph-capturable)
  hipMemsetAsync(d_ws, 0, 128 * sizeof(unsigned int), stream);
  lstm2_kernel<<<dim3(256), dim3(512), 0, stream>>>(
      (const float*)d_in[0],   // x
      (const float*)d_in[1],   // w_ih1
      (const float*)d_in[2],   // w_hh1
      (const float*)d_in[3],   // b_ih1
      (const float*)d_in[4],   // b_hh1
      (const float*)d_in[5],   // w_ih2
      (const float*)d_in[6],   // w_hh2
      (const float*)d_in[7],   // b_ih2
      (const float*)d_in[8],   // b_hh2
      (float*)d_out,
      (unsigned int*)d_ws);
}

// Round 9
// 592.491 us; speedup vs baseline: 4.9915x; 4.9915x over previous
//
#include <hip/hip_runtime.h>

// 2-layer LSTM encoder, B=128, T=1024, F=1, HID=128, EMB=64.
// R18 = split-CU pipeline, chunked handoff (R15's two measured failure
// causes fixed; R16/R17's LDS-spin mechanism abandoned as unexplained).
//   blocks 0..127  = L1 producers (8 waves, R9-verified map, 620cy/SIMD pipe):
//     - per-step RAW barrier (s_waitcnt lgkmcnt(0) + s_barrier; HK pattern,
//       m194-m201): global ring stores stay in flight across steps -- fixes
//       R15's per-step vmcnt(0) drain (~700cy/step).
//     - h1(s) -> own LDS ring (recurrence) + f32 agent-atomic store to
//       global ring[bb][chunk&7][step&7][cell] (visibility proven in R15).
//     - chunk flag (8 steps) published 2 steps late after counted
//       s_waitcnt vmcnt(2) (in-flight = 2 newest stores -> chunk fully
//       retired; wait is instant). Cost ~0.
//     - back-pressure once per chunk: consFlag >= C-7 before overwriting
//       ring slot C&7 (fixes R15's race). Cached; bounded poll.
//   blocks 128..255 = L2 consumers (waves 0-3 compute = R14-verified map,
//     wave 4 = stager, waves 5-7 barrier-idle; plain __syncthreads per step):
//     - stager: per chunk, ONE acquire poll of prodFlag (emits buffer_inv ->
//       fresh LLC reads), 64B/lane f32 loads, rte cvt to f16, ds_write into
//       SH1 double buffer, then consFlag/readyUpTo publish. Staged one chunk
//       ahead; LLC latency amortized to ~90cy/step, off critical path.
//     - chunk gate: convergent barrier-paced retry loop on LDS readyUpTo
//       (plain LDS + __syncthreads ordering only -- no free-running spin).
//   ALL polls bounded (~1<<20 iters): worst-case bug = wrong answer, not a
//   dead container.
// Workspace: prodFlag[128] consFlag[128] (zeroed per launch) + f32 ring
//   128*8*8*128 = 4 MB.
// Numerics: h1 f32 -> rte f16 on stage = identical rounding to the old
//   shared-LDS path; absmax must be exactly 4.882812e-4 (drift = race).

#define TB   1024
#define HID1 128
#define EMB2 64

typedef _Float16 f16x8 __attribute__((ext_vector_type(8)));
typedef float    f32x4 __attribute__((ext_vector_type(4)));

#define MFMA16(a,b,c) __builtin_amdgcn_mfma_f32_16x16x32_f16((a),(b),(c),0,0,0)

static __device__ __forceinline__ float fast_exp2(float x){
#if __has_builtin(__builtin_amdgcn_exp2f)
  return __builtin_amdgcn_exp2f(x);
#else
  return __exp2f(x);
#endif
}
static __device__ __forceinline__ float fast_rcp(float x){
#if __has_builtin(__builtin_amdgcn_rcpf)
  return __builtin_amdgcn_rcpf(x);
#else
  return 1.0f / x;
#endif
}
static __device__ __forceinline__ float sigmoid_f(float x){
  return fast_rcp(1.0f + fast_exp2(-1.44269504088896340736f * x));
}
static __device__ __forceinline__ float tanh_f(float x){
  return 1.0f - 2.0f * fast_rcp(1.0f + fast_exp2(2.88539008177792681472f * x));
}

static __device__ __forceinline__ f16x8 load_frag(const float* p){
  f16x8 r;
  #pragma unroll
  for (int j = 0; j < 8; ++j) r[j] = (_Float16)p[j];
  return r;
}

// HK-verified barrier without vmcnt drain (stores stay in flight).
#define RAWBAR() do {                                          \
    asm volatile("s_waitcnt lgkmcnt(0)" ::: "memory");         \
    __builtin_amdgcn_s_barrier();                              \
    __builtin_amdgcn_sched_barrier(0);                         \
  } while(0)

__launch_bounds__(512, 1)
__global__ void lstm2_kernel(const float* __restrict__ x,
                             const float* __restrict__ w_ih1,
                             const float* __restrict__ w_hh1,
                             const float* __restrict__ b_ih1,
                             const float* __restrict__ b_hh1,
                             const float* __restrict__ w_ih2,
                             const float* __restrict__ w_hh2,
                             const float* __restrict__ b_ih2,
                             const float* __restrict__ b_hh2,
                             float* __restrict__ out,
                             unsigned* __restrict__ ws)
{
  __shared__ __align__(16) float    xs[TB];            // producer
  __shared__ __align__(16) _Float16 H1R[8][HID1];      // producer h1 ring
  __shared__ __align__(16) _Float16 SH1[2][8][HID1];   // consumer staged h1 (dbuf)
  __shared__ __align__(16) _Float16 H2R[8][EMB2];      // consumer h2 ring
  __shared__ unsigned readyUpTo;                       // consumer chunk gate

  const int t    = threadIdx.x;   // 0..511
  const int l    = t & 63;
  const int w    = t >> 6;        // wave 0..7
  const int col  = l & 15;
  const int quad = l >> 4;

  unsigned* prodFlag = ws;          // [128] chunks published
  unsigned* consFlag = ws + 128;    // [128] chunks consumed (ring reads done)
  unsigned* ring     = ws + 256;    // [128][8][8][128] f32 bits

  const f32x4 zacc = {0.0f, 0.0f, 0.0f, 0.0f};

  if (blockIdx.x < 128){
    // ===================== L1 PRODUCER (batch bb) =====================
    const int bb = blockIdx.x;
    f16x8 B1[16];                    // [g][k] flattened
    float biasA[4], wxA[4];
    #pragma unroll
    for (int g = 0; g < 4; ++g){
      const int nA = (w + 8*g)*16 + col;
      biasA[g] = b_ih1[nA] + b_hh1[nA];
      wxA[g]   = w_ih1[nA];                    // w_ih1 is (512,1)
      #pragma unroll
      for (int k = 0; k < 4; ++k)
        B1[4*g + k] = load_frag(w_hh1 + nA*HID1 + k*32 + quad*8);
    }
    xs[t]       = x[bb * TB + t];
    xs[t + 512] = x[bb * TB + t + 512];
    __syncthreads();

    float c1 = 0.0f;
    const int cellA = 16*w + l;      // valid when l<16

    // step 0: h1(0) = f(x0), no MFMA
    if (l < 16){
      const float xt = xs[0];
      float g4[4];
      #pragma unroll
      for (int g = 0; g < 4; ++g) g4[g] = __builtin_fmaf(xt, wxA[g], biasA[g]);
      c1 = sigmoid_f(g4[1]) * c1 + sigmoid_f(g4[0]) * tanh_f(g4[2]);
      const float hv = sigmoid_f(g4[3]) * tanh_f(c1);
      H1R[0][cellA] = (_Float16)hv;
      __hip_atomic_store(&ring[(unsigned)(bb*8 + 0)*1024u + (unsigned)cellA],
                         __float_as_uint(hv),
                         __ATOMIC_RELAXED, __HIP_MEMORY_SCOPE_AGENT);
    }

    unsigned cachedCons = 0;
    #pragma unroll 1
    for (int s = 1; s < TB; ++s){
      const bool pub = ((s & 7) == 2) && (s >= 10);
      if (pub) asm volatile("s_waitcnt vmcnt(2)" ::: "memory");  // chunk retired
      RAWBAR();
      if (pub && w == 0 && l == 0)
        __hip_atomic_store(&prodFlag[bb], (unsigned)(((s - 10) >> 3) + 1),
                           __ATOMIC_RELAXED, __HIP_MEMORY_SCOPE_AGENT);
      if (((s & 7) == 0) && s >= 64){
        // back-pressure: about to overwrite ring slot (s>>3)&7 (chunk C-8)
        if (w == 0 && l == 0){
          const unsigned need = (unsigned)((s >> 3) - 7);
          if (cachedCons < need){
            int gd = 0;
            while (cachedCons < need && gd++ < (1 << 20)){
              cachedCons = __hip_atomic_load(&consFlag[bb], __ATOMIC_ACQUIRE,
                                             __HIP_MEMORY_SCOPE_AGENT);
              if (cachedCons < need) __builtin_amdgcn_s_sleep(2);
            }
          }
        }
        RAWBAR();   // hold all waves until wave 0 clears back-pressure
      }

      const f16x8* pA1 = (const f16x8*)&H1R[(s-1)&7][0];
      const f16x8 a10 = pA1[quad],     a11 = pA1[4+quad],
                  a12 = pA1[8+quad],   a13 = pA1[12+quad];
      f32x4 aLo[4], aHi[4];
      #pragma unroll
      for (int g = 0; g < 4; ++g){
        aLo[g] = MFMA16(a10, B1[4*g+0], zacc);
        aHi[g] = MFMA16(a12, B1[4*g+2], zacc);
      }
      #pragma unroll
      for (int g = 0; g < 4; ++g){
        aLo[g] = MFMA16(a11, B1[4*g+1], aLo[g]);
        aHi[g] = MFMA16(a13, B1[4*g+3], aHi[g]);
      }
      if (l < 16){
        float g4[4];
        #pragma unroll
        for (int g = 0; g < 4; ++g)
          g4[g] = aLo[g][0] + aHi[g][0] + __builtin_fmaf(xs[s], wxA[g], biasA[g]);
        c1 = sigmoid_f(g4[1]) * c1 + sigmoid_f(g4[0]) * tanh_f(g4[2]);
        const float hv = sigmoid_f(g4[3]) * tanh_f(c1);
        H1R[s&7][cellA] = (_Float16)hv;
        __hip_atomic_store(&ring[(unsigned)(bb*8 + ((s>>3)&7))*1024u
                                 + (unsigned)(s&7)*128u + (unsigned)cellA],
                           __float_as_uint(hv),
                           __ATOMIC_RELAXED, __HIP_MEMORY_SCOPE_AGENT);
      }
    }
    // final: drain everything, publish chunk 127 (flag = 128)
    asm volatile("s_waitcnt vmcnt(0)" ::: "memory");
    RAWBAR();
    if (w == 0 && l == 0)
      __hip_atomic_store(&prodFlag[bb], 128u,
                         __ATOMIC_RELEASE, __HIP_MEMORY_SCOPE_AGENT);

  } else {
    // ===================== L2 CONSUMER (batch bb) =====================
    const int bb = blockIdx.x - 128;
    f16x8 B2i[16], B2h[8];
    float biasB[4] = {0,0,0,0};
    if (w < 4){
      #pragma unroll
      for (int g = 0; g < 4; ++g){
        const int nB = (4*g + w)*16 + col;
        biasB[g] = b_ih2[nB] + b_hh2[nB];
        #pragma unroll
        for (int k = 0; k < 4; ++k)
          B2i[4*g + k] = load_frag(w_ih2 + nB*HID1 + k*32 + quad*8);
        #pragma unroll
        for (int k = 0; k < 2; ++k)
          B2h[2*g + k] = load_frag(w_hh2 + nB*EMB2 + k*32 + quad*8);
      }
    }
    if (t < EMB2) H2R[7][t] = (_Float16)0.0f;   // h2(-1) = 0
    if (t == 0) readyUpTo = 0u;
    __syncthreads();

    unsigned staged = 0;   // stager (wave 4) private progress
    float c2 = 0.0f;

    // stage attempt: one fresh acquire poll (buffer_inv), then load+cvt+write.
    #define STAGE_ATTEMPT() do {                                              \
        if (staged < 128u){                                                   \
          const unsigned pf_ = __hip_atomic_load(&prodFlag[bb],               \
                                  __ATOMIC_ACQUIRE, __HIP_MEMORY_SCOPE_AGENT);\
          asm volatile("" ::: "memory");                                      \
          __builtin_amdgcn_sched_barrier(0);                                  \
          if (pf_ > staged){                                                  \
            const float4* rp_ = (const float4*)(ring                          \
                + (unsigned)(bb*8 + (staged&7))*1024u + (unsigned)l*16u);     \
            const float4 v0_ = rp_[0], v1_ = rp_[1],                          \
                         v2_ = rp_[2], v3_ = rp_[3];                          \
            f16x8 p0_, p1_;                                                   \
            p0_[0]=(_Float16)v0_.x; p0_[1]=(_Float16)v0_.y;                   \
            p0_[2]=(_Float16)v0_.z; p0_[3]=(_Float16)v0_.w;                   \
            p0_[4]=(_Float16)v1_.x; p0_[5]=(_Float16)v1_.y;                   \
            p0_[6]=(_Float16)v1_.z; p0_[7]=(_Float16)v1_.w;                   \
            p1_[0]=(_Float16)v2_.x; p1_[1]=(_Float16)v2_.y;                   \
            p1_[2]=(_Float16)v2_.z; p1_[3]=(_Float16)v2_.w;                   \
            p1_[4]=(_Float16)v3_.x; p1_[5]=(_Float16)v3_.y;                   \
            p1_[6]=(_Float16)v3_.z; p1_[7]=(_Float16)v3_.w;                   \
            f16x8* dst_ = (f16x8*)&SH1[staged&1][0][0];                       \
            dst_[2*l] = p0_; dst_[2*l+1] = p1_;                               \
            asm volatile("" ::: "memory");                                    \
            if (l == 0){                                                      \
              __hip_atomic_store(&consFlag[bb], staged + 1u,                  \
                  __ATOMIC_RELAXED, __HIP_MEMORY_SCOPE_AGENT);                \
              readyUpTo = staged + 1u;                                        \
            }                                                                 \
            staged++;                                                         \
          }                                                                   \
        }                                                                     \
      } while(0)

    #pragma unroll 1
    for (int m = 0; m < TB; ++m){
      const int c = m >> 3;
      if ((m & 7) == 0){
        // convergent barrier-paced gate: wait until chunk c staged
        int gd = 0;
        while (*(volatile unsigned*)&readyUpTo < (unsigned)(c + 1)
               && gd++ < (1 << 20)){
          if (w == 4) STAGE_ATTEMPT();
          __syncthreads();
        }
        if (w == 4) STAGE_ATTEMPT();   // opportunistic prefetch of chunk c+1
      }

      if (w < 4){
        const f16x8* pA2 = (const f16x8*)&H2R[(m+7)&7][0];     // h2(m-1)
        const f16x8 a20 = pA2[quad], a21 = pA2[4+quad];
        const f16x8* pA1 = (const f16x8*)&SH1[c&1][m&7][0];    // staged h1(m)
        const f16x8 a10 = pA1[quad],    a11 = pA1[4+quad],
                    a12 = pA1[8+quad],  a13 = pA1[12+quad];
        f32x4 lo[4], hi[4];
        #pragma unroll
        for (int g = 0; g < 4; ++g){
          lo[g] = MFMA16(a10, B2i[4*g+0], zacc);
          hi[g] = MFMA16(a12, B2i[4*g+2], zacc);
        }
        #pragma unroll
        for (int g = 0; g < 4; ++g){
          lo[g] = MFMA16(a11, B2i[4*g+1], lo[g]);
          hi[g] = MFMA16(a13, B2i[4*g+3], hi[g]);
        }
        #pragma unroll
        for (int g = 0; g < 4; ++g){
          lo[g] = MFMA16(a20, B2h[2*g+0], lo[g]);
          hi[g] = MFMA16(a21, B2h[2*g+1], hi[g]);
        }
        if (l < 16){
          float g4[4];
          #pragma unroll
          for (int g = 0; g < 4; ++g) g4[g] = lo[g][0] + hi[g][0] + biasB[g];
          c2 = sigmoid_f(g4[1]) * c2 + sigmoid_f(g4[0]) * tanh_f(g4[2]);
          const float hv = sigmoid_f(g4[3]) * tanh_f(c2);
          if (m < TB-1) H2R[m&7][16*w + l] = (_Float16)hv;
          else          out[bb * EMB2 + 16*w + l] = hv;
        }
      }
      __syncthreads();
    }
    #undef STAGE_ATTEMPT
  }
}

extern "C" void kernel_launch(void* const* d_in, const int* in_sizes, int n_in,
                              void* d_out, int out_size, void* d_ws, size_t ws_size,
                              hipStream_t stream) {
  // zero the 256 flag counters each launch (stream-ordered, graph-capturable)
  hipMemsetAsync(d_ws, 0, 256 * sizeof(unsigned), stream);
  lstm2_kernel<<<dim3(256), dim3(512), 0, stream>>>(
      (const float*)d_in[0],   // x
      (const float*)d_in[1],   // w_ih1
      (const float*)d_in[2],   // w_hh1
      (const float*)d_in[3],   // b_ih1
      (const float*)d_in[4],   // b_hh1
      (const float*)d_in[5],   // w_ih2
      (const float*)d_in[6],   // w_hh2
      (const float*)d_in[7],   // b_ih2
      (const float*)d_in[8],   // b_hh2
      (float*)d_out,
      (unsigned*)d_ws);
}